// Round 6
// baseline (232.966 us; speedup 1.0000x reference)
//
#include <hip/hip_runtime.h>
#include <hip/hip_fp8.h>

#define LOGZERO -4290774016.0f   // -(65504^2), exactly representable in fp32
#define L2E 1.4426950408889634f  // log2(e)
#define LN2 0.6931471805599453f

constexpr int Bb = 32, Tt = 512, Dd = 512, Vv = 4096;
constexpr int BT = Bb * Tt;

typedef __attribute__((ext_vector_type(4)))  float f32x4;
typedef __attribute__((ext_vector_type(16))) float f32x16;
typedef __attribute__((ext_vector_type(4)))  int   i32x4;
typedef __attribute__((ext_vector_type(8)))  int   i32x8;

#define GLOBAL_AS __attribute__((address_space(1)))
#define LDS_AS    __attribute__((address_space(3)))

__device__ __forceinline__ float fexp2(float x) { return __builtin_amdgcn_exp2f(x); }  // 2^x
__device__ __forceinline__ float flog2(float x) { return __builtin_amdgcn_logf(x); }   // log2(x)

// pack 4 floats (scaled) -> 4 OCP e4m3 bytes
__device__ __forceinline__ unsigned cvt4_fp8(float4 v, float s) {
#if __has_builtin(__builtin_amdgcn_cvt_pk_fp8_f32)
  int p = __builtin_amdgcn_cvt_pk_fp8_f32(v.x * s, v.y * s, 0, false);
  p = __builtin_amdgcn_cvt_pk_fp8_f32(v.z * s, v.w * s, p, true);
  return (unsigned)p;
#else
  unsigned b0 = __hip_cvt_float_to_fp8(v.x * s, __HIP_SATFINITE, __HIP_E4M3);
  unsigned b1 = __hip_cvt_float_to_fp8(v.y * s, __HIP_SATFINITE, __HIP_E4M3);
  unsigned b2 = __hip_cvt_float_to_fp8(v.z * s, __HIP_SATFINITE, __HIP_E4M3);
  unsigned b3 = __hip_cvt_float_to_fp8(v.w * s, __HIP_SATFINITE, __HIP_E4M3);
  return b0 | (b1 << 8) | (b2 << 16) | (b3 << 24);
#endif
}

// logaddexp in the log2 domain
__device__ __forceinline__ float lg2add(float a, float b) {
  float mx = fmaxf(a, b);
  float d  = fabsf(a - b);
  return mx + flog2(1.0f + fexp2(-d));
}

// ---- kPre v2: LDS-transposed coalesced pack into fp8 fragment layouts ----
// R5 lesson: the R3 kPre read x/W with lane==row (2-KB stride) -> 64 scattered
// line requests per load instr. v2: one block per 32-row output tile.
//   Phase 1: 16 passes; pass p, thread i handles float4 index f=p*256+i of the
//     64-KB source region -> per-instr the wave reads a CONTIGUOUS 1-KB burst.
//     Convert to 4 fp8 bytes, store to LDS at swizzled (r,c): r=f>>7, c=(f&127)>>2,
//     m=f&3; addr = (r*32 + (c^r))*16 + m*4. XOR swizzle: write banks 2-way (free),
//     phase-2 b128 reads spread over 8 bank-start groups (minimum aliasing).
//   Phase 2: thread writes output slots s=u*256+i: 16-B ds_read_b128 + 1-KB
//     coalesced global stores. Output bytes IDENTICAL to R5 layouts:
// Xfp tile tM (16 KB): slot16 = (kb*2+h)*64 + khalf*32 + r
//   = fp8( x[tM*32+r][kb*64 + khalf*32 + h*16 + j] ), j=0..15
// Wp tile cb (32 KB): slot16 = (kb*4+ct*2+h)*64 + khalf*32 + r
//   = fp8( 16 * W[cb*64+ct*32+r][kb*64 + khalf*32 + h*16 + j] )
// Grid: 512 X blocks + 128 W blocks (W block = one ct-half of a cb tile).
__global__ __launch_bounds__(256) void kPre(const float* __restrict__ x,
                                            const float* __restrict__ W,
                                            unsigned char* __restrict__ Xfp,
                                            unsigned char* __restrict__ Wp) {
  __shared__ unsigned char T[16384];
  const int tid = threadIdx.x, bid = blockIdx.x;
  const bool isX = bid < 512;
  const float* srcF;
  float scale;
  int cb = 0, half = 0;
  if (isX) {
    srcF = x + (size_t)bid * 32 * Dd;            // 32 contiguous rows
    scale = 1.0f;
  } else {
    int idx = bid - 512;                          // 0..127
    cb = idx >> 1; half = idx & 1;
    srcF = W + ((size_t)cb * 64 + half * 32) * Dd;
    scale = 16.0f;                                // x16 prescale (undone by MX scale_b)
  }

  // phase 1: fully-coalesced loads -> fp8 -> swizzled LDS
  #pragma unroll
  for (int p = 0; p < 16; ++p) {
    int f = p * 256 + tid;                        // float4 index 0..4095
    int r = f >> 7;                               // row 0..31
    int cf = f & 127;
    int c = cf >> 2, m = cf & 3;                  // 16-float chunk, float4 within
    float4 v = *(const float4*)(srcF + (size_t)f * 4);
    unsigned o = cvt4_fp8(v, scale);
    *(unsigned*)(T + ((r * 32 + (c ^ r)) * 16 + m * 4)) = o;
  }
  __syncthreads();

  // phase 2: gather fragment slots, 1-KB coalesced stores
  if (isX) {
    unsigned char* dst = Xfp + (size_t)bid * 16384;
    #pragma unroll
    for (int u = 0; u < 4; ++u) {
      int s = u * 256 + tid;                      // slot 0..1023
      int r = s & 31, khalf = (s >> 5) & 1, h = (s >> 6) & 1, kb = s >> 7;
      int c = kb * 4 + khalf * 2 + h;
      uint4 o = *(const uint4*)(T + (r * 32 + (c ^ r)) * 16);
      *(uint4*)(dst + (size_t)s * 16) = o;
    }
  } else {
    unsigned char* dst = Wp + (size_t)cb * 32768;
    #pragma unroll
    for (int u = 0; u < 4; ++u) {
      int lsl = u * 256 + tid;                    // local slot 0..1023 (ct=half)
      int r = lsl & 31, khalf = (lsl >> 5) & 1, h = (lsl >> 6) & 1, kb = lsl >> 7;
      int c = kb * 4 + khalf * 2 + h;
      int s = kb * 256 + half * 128 + h * 64 + khalf * 32 + r;
      uint4 o = *(const uint4*)(T + (r * 32 + (c ^ r)) * 16);
      *(uint4*)(dst + (size_t)s * 16) = o;
    }
  }
}

// ---- barrier-free MX-fp8 GEMM + exp-sum partials + beam scatter, M_tile=32 ----
// UNCHANGED from R5 (the control this round). grid 8192, 256 threads.
// 6 blk/CU, 16 MFMA/wave mfma_scale_f32_32x32x64_f8f6f4; scalarized scatter.
__global__ __launch_bounds__(256, 6) void kA(const unsigned char* __restrict__ Xfp,
                                             const unsigned char* __restrict__ Wp,
                                             const float* __restrict__ bias,
                                             const int* __restrict__ beam,
                                             const int* __restrict__ blankp,
                                             float* __restrict__ Spart,
                                             float* __restrict__ selL,
                                             int CB) {
  __shared__ unsigned char Ald[16384];   // packed A tile (32 rows x 512 K)
  __shared__ float Spw[4][32];
  __shared__ int   selv[31];
  __shared__ float selb[31];

  const int tid = threadIdx.x;
  const int tileN = blockIdx.x & 15;
  const int tileM = blockIdx.x >> 4;     // 0..511 (32-row tiles)
  const int row0 = tileM * 32, col0 = tileN * 256;
  const int bb = row0 >> 9;              // batch of this block (32 | 512)
  const int lane = tid & 63, w = tid >> 6;
  const int l31 = lane & 31, hi = lane >> 5;

  if (tid < 31) {
    int v = (tid == 0) ? *blankp : beam[bb * CB + tid - 1];
    selv[tid] = v;
    selb[tid] = bias[v];
  }

  // stage packed A tile: 16 x 1KB fully-linear DMA bursts (wave w does 4)
  const unsigned char* src = Xfp + (size_t)tileM * 16384;
  #pragma unroll
  for (int i = 0; i < 4; ++i) {
    int off = (w * 4 + i) * 1024;
    __builtin_amdgcn_global_load_lds((const GLOBAL_AS void*)(src + off + lane * 16),
                                     (LDS_AS void*)(Ald + off), 16, 0, 0);
  }
  __syncthreads();                       // only barrier before epilogue

  const int colw = col0 + w * 64;
  const int cb = tileN * 4 + w;

  f32x16 acc[2];                         // acc[ct], 32x32 each
  #pragma unroll
  for (int ct = 0; ct < 2; ++ct)
    #pragma unroll
    for (int r = 0; r < 16; ++r) acc[ct][r] = 0.f;

  const unsigned char* wpB = Wp + (size_t)cb * 32768 + lane * 16;

  i32x8 bc[2];
  #pragma unroll
  for (int ct = 0; ct < 2; ++ct) {
    i32x4 lo = *(const i32x4*)(wpB + (ct * 2) * 1024);
    i32x4 hx = *(const i32x4*)(wpB + (ct * 2 + 1) * 1024);
    bc[ct] = __builtin_shufflevector(lo, hx, 0, 1, 2, 3, 4, 5, 6, 7);
  }

  #pragma unroll
  for (int kb = 0; kb < 8; ++kb) {
    i32x8 af;
    {                                    // linear conflict-free b128 pair
      i32x4 lo = *(const i32x4*)&Ald[(kb * 2) * 1024 + lane * 16];
      i32x4 hx = *(const i32x4*)&Ald[(kb * 2 + 1) * 1024 + lane * 16];
      af = __builtin_shufflevector(lo, hx, 0, 1, 2, 3, 4, 5, 6, 7);
    }
    i32x8 bn[2];
    const int kn = (kb < 7) ? kb + 1 : 7;   // depth-1 B prefetch
    #pragma unroll
    for (int ct = 0; ct < 2; ++ct) {
      i32x4 lo = *(const i32x4*)(wpB + (kn * 4 + ct * 2) * 1024);
      i32x4 hx = *(const i32x4*)(wpB + (kn * 4 + ct * 2 + 1) * 1024);
      bn[ct] = __builtin_shufflevector(lo, hx, 0, 1, 2, 3, 4, 5, 6, 7);
    }
    #pragma unroll
    for (int ct = 0; ct < 2; ++ct)
      acc[ct] = __builtin_amdgcn_mfma_scale_f32_32x32x64_f8f6f4(
          af, bc[ct], acc[ct],
          0, 0,                           // cbsz=fp8(A), blgp=fp8(B)
          0, 0x7f7f7f7f,                  // scale_a = 2^0  (e8m0 127)
          0, 0x7b7b7b7b);                 // scale_b = 2^-4 (e8m0 123)
    bc[0] = bn[0]; bc[1] = bn[1];
  }

  // epilogue 1: row-wise sum(exp(logit+bias)) -> per-block partial (no atomics)
  // C layout (32x32): col = ct*32 + l31, row = (reg&3) + 8*(reg>>2) + 4*hi
  float bvl[2];
  #pragma unroll
  for (int ct = 0; ct < 2; ++ct)
    bvl[ct] = bias[colw + ct * 32 + l31] * L2E;

  #pragma unroll
  for (int reg = 0; reg < 16; ++reg) {
    float s = fexp2(acc[0][reg] * L2E + bvl[0]) +
              fexp2(acc[1][reg] * L2E + bvl[1]);
    s += __shfl_xor(s, 1, 64);            // reduce over 32 cols (lane bits 0..4;
    s += __shfl_xor(s, 2, 64);            //  hi-bit lanes hold different rows,
    s += __shfl_xor(s, 4, 64);            //  never mixed by this tree)
    s += __shfl_xor(s, 8, 64);
    s += __shfl_xor(s, 16, 64);
    if (l31 == 0)
      Spw[w][(reg & 3) + 8 * (reg >> 2) + 4 * hi] = s;
  }
  __syncthreads();
  if (tid < 32) {
    float p = Spw[0][tid] + Spw[1][tid] + Spw[2][tid] + Spw[3][tid];
    Spart[(size_t)tileN * BT + row0 + tid] = p;
  }

  // epilogue 2: beam-column scatter (raw ln-domain logit + bias).
  // selv[s]/colw wave-uniform -> readfirstlane + scalar branch skips ~29/31
  // beams with zero VALU. ct static (no runtime acc indexing).
  const int tbase = row0 & 511;
  #pragma unroll 1
  for (int s = 0; s < 31; ++s) {
    const int vsel = __builtin_amdgcn_readfirstlane(selv[s]);
    const int local = vsel - colw;
    if (local >= 0 && local < 32) {       // scalar branch, ct = 0
      const float bvs = selb[s];
      if (l31 == local) {
        #pragma unroll
        for (int reg = 0; reg < 16; ++reg) {
          int t = tbase + (reg & 3) + 8 * (reg >> 2) + 4 * hi;
          selL[((size_t)bb * Tt + t) * 31 + s] = acc[0][reg] + bvs;
        }
      }
    } else if (local >= 32 && local < 64) {  // scalar branch, ct = 1
      const float bvs = selb[s];
      if (l31 == (local & 31)) {
        #pragma unroll
        for (int reg = 0; reg < 16; ++reg) {
          int t = tbase + (reg & 3) + 8 * (reg >> 2) + 4 * hi;
          selL[((size_t)bb * Tt + t) * 31 + s] = acc[1][reg] + bvs;
        }
      }
    }
  }
}

// ---- CTC DP + output assembly, log2 domain. grid: B blocks x 256 threads ----
// R6 changes: (1) lgS computed FIRST and folded into sl at staging time
// (removes one ds_read + sub per DP iteration; blankLp array eliminated);
// (2) DP loop software-pipelined with depth-1 register prefetch of xn/xb/pref
// so the ~120-cyc LDS read latency hides under the lg2add chains.
__global__ __launch_bounds__(256) void kC(const float* __restrict__ selL,
                                          const float* __restrict__ Spart,
                                          const int* __restrict__ xl,
                                          const int* __restrict__ beam,
                                          const int* __restrict__ blankp,
                                          const int* __restrict__ eosp,
                                          float* __restrict__ out,
                                          int Ly, int CB) {
  __shared__ float sl[Tt * 31];     // log2-domain logp of selected cols
  __shared__ float lgS[Tt];         // log2(sum_exp)
  __shared__ float lastP1[Tt];      // log2-domain blank cumsum
  const int b = blockIdx.x, tid = threadIdx.x;

  for (int tt = tid; tt < Tt; tt += 256) {
    float s = 0.f;
    #pragma unroll
    for (int n = 0; n < 16; ++n) s += Spart[(size_t)n * BT + b * Tt + tt];
    lgS[tt] = flog2(s);
  }
  __syncthreads();
  for (int i = tid; i < Tt * 31; i += 256) {
    int t = i / 31;                   // const-div -> magic mul
    sl[i] = selL[(size_t)b * Tt * 31 + i] * L2E - lgS[t];
  }
  __syncthreads();

  float* orow = out + (size_t)b * Vv;
  for (int i = tid; i < Vv; i += 256) orow[i] = LOGZERO;

  const int xlb = xl[b];
  float curP = LOGZERO;
  if (tid < 64) {
    const int lane = tid;
    float vloc[8];
    float run = 0.f;
    #pragma unroll
    for (int u = 0; u < 8; ++u) {
      int t = lane * 8 + u;
      float bl = sl[t * 31];          // already log-softmax'd
      run += bl;
      vloc[u] = run;
    }
    float inc = run;
    #pragma unroll
    for (int off = 1; off < 64; off <<= 1) {
      float o = __shfl_up(inc, off, 64);
      if (lane >= off) inc += o;
    }
    float excl = inc - run;
    #pragma unroll
    for (int u = 0; u < 8; ++u) lastP1[lane * 8 + u] = vloc[u] + excl;

    const int kk = (lane < CB) ? lane : (CB - 1);
    const float LOG2ZERO = LOGZERO * L2E;
    float Pn = LOG2ZERO, Pb = LOG2ZERO;
    float mrun = -3.0e38f, srun = 0.0f;
    int start = (Ly < Tt - 1) ? Ly : (Tt - 1);
    if (start == 0) {
      Pn = sl[1 + kk];
      float vv = (0 < xlb) ? lg2add(Pn, Pb) : LOG2ZERO;
      float nm = fmaxf(mrun, vv);
      srun = srun * fexp2(mrun - nm) + fexp2(vv - nm);
      mrun = nm;
    }
    int t0 = (start > 1) ? start : 1;
    // depth-1 prefetch: current values in regs, next iter's loads issued early
    float xn_c = sl[t0 * 31 + 1 + kk];
    float xb_c = sl[t0 * 31];
    float pf_c = lastP1[t0 - 1];      // lastPsum == lastP1 bit-exactly
    #pragma unroll 2
    for (int t = t0; t < Tt; ++t) {
      float xn_n = 0.f, xb_n = 0.f, pf_n = 0.f;
      if (t + 1 < Tt) {
        xn_n = sl[(t + 1) * 31 + 1 + kk];
        xb_n = sl[(t + 1) * 31];
        pf_n = lastP1[t];
      }
      float Pn2 = lg2add(Pn, pf_c) + xn_c;
      float Pb2 = lg2add(Pn, Pb) + xb_c;
      Pn = Pn2; Pb = Pb2;
      float vv = (t < xlb) ? lg2add(Pn, Pb) : LOG2ZERO;   // off critical path
      float nm = fmaxf(mrun, vv);
      srun = srun * fexp2(mrun - nm) + fexp2(vv - nm);
      mrun = nm;
      xn_c = xn_n; xb_c = xb_n; pf_c = pf_n;
    }
    curP = (mrun + flog2(srun)) * LN2;       // back to ln domain
  }
  __syncthreads();   // LOGZERO fill + lastP1 complete

  if (tid < 64) {
    if (tid < CB) orow[beam[b * CB + tid]] = curP;
  }
  __syncthreads();
  if (tid == 0) {
    float eosv = (xlb >= 1) ? lastP1[xlb - 1] * LN2 : 0.0f;
    orow[*eosp] = eosv;
    orow[*blankp] = LOGZERO;
  }
}

extern "C" void kernel_launch(void* const* d_in, const int* in_sizes, int n_in,
                              void* d_out, int out_size, void* d_ws, size_t ws_size,
                              hipStream_t stream) {
  (void)n_in; (void)out_size; (void)ws_size;
  const float* x    = (const float*)d_in[0];
  const float* W    = (const float*)d_in[1];
  const float* bias = (const float*)d_in[2];
  const int* xl     = (const int*)d_in[3];
  const int* beam   = (const int*)d_in[5];
  const int* blankp = (const int*)d_in[6];
  const int* eosp   = (const int*)d_in[7];
  const int Ly = in_sizes[4] / Bb;
  const int CB = in_sizes[5] / Bb;

  float* Spart = (float*)d_ws;                                            // 1 MB
  float* selL  = (float*)((char*)d_ws + (size_t)0x100000);                // 2.03 MB
  unsigned char* Xfp = (unsigned char*)((char*)d_ws + (size_t)0x400000);  // 8 MB
  unsigned char* Wp  = (unsigned char*)((char*)d_ws + (size_t)0xC00000);  // 2 MB
  float* outf = (float*)d_out;

  kPre<<<640, 256, 0, stream>>>(x, W, Xfp, Wp);
  kA<<<8192, 256, 0, stream>>>(Xfp, Wp, bias, beam, blankp, Spart, selL, CB);
  kC<<<Bb, 256, 0, stream>>>(selL, Spart, xl, beam, blankp, eosp, outf, Ly, CB);
}

// Round 7
// 232.918 us; speedup vs baseline: 1.0002x; 1.0002x over previous
//
#include <hip/hip_runtime.h>
#include <hip/hip_fp8.h>

#define LOGZERO -4290774016.0f   // -(65504^2), exactly representable in fp32
#define L2E 1.4426950408889634f  // log2(e)
#define LN2 0.6931471805599453f

constexpr int Bb = 32, Tt = 512, Dd = 512, Vv = 4096;
constexpr int BT = Bb * Tt;

typedef __attribute__((ext_vector_type(4)))  float f32x4;
typedef __attribute__((ext_vector_type(16))) float f32x16;
typedef __attribute__((ext_vector_type(4)))  int   i32x4;
typedef __attribute__((ext_vector_type(8)))  int   i32x8;

#define GLOBAL_AS __attribute__((address_space(1)))
#define LDS_AS    __attribute__((address_space(3)))

__device__ __forceinline__ float fexp2(float x) { return __builtin_amdgcn_exp2f(x); }  // 2^x
__device__ __forceinline__ float flog2(float x) { return __builtin_amdgcn_logf(x); }   // log2(x)

// pack 4 floats (scaled) -> 4 OCP e4m3 bytes
__device__ __forceinline__ unsigned cvt4_fp8(float4 v, float s) {
#if __has_builtin(__builtin_amdgcn_cvt_pk_fp8_f32)
  int p = __builtin_amdgcn_cvt_pk_fp8_f32(v.x * s, v.y * s, 0, false);
  p = __builtin_amdgcn_cvt_pk_fp8_f32(v.z * s, v.w * s, p, true);
  return (unsigned)p;
#else
  unsigned b0 = __hip_cvt_float_to_fp8(v.x * s, __HIP_SATFINITE, __HIP_E4M3);
  unsigned b1 = __hip_cvt_float_to_fp8(v.y * s, __HIP_SATFINITE, __HIP_E4M3);
  unsigned b2 = __hip_cvt_float_to_fp8(v.z * s, __HIP_SATFINITE, __HIP_E4M3);
  unsigned b3 = __hip_cvt_float_to_fp8(v.w * s, __HIP_SATFINITE, __HIP_E4M3);
  return b0 | (b1 << 8) | (b2 << 16) | (b3 << 24);
#endif
}

// logaddexp in the log2 domain
__device__ __forceinline__ float lg2add(float a, float b) {
  float mx = fmaxf(a, b);
  float d  = fabsf(a - b);
  return mx + flog2(1.0f + fexp2(-d));
}

// load two b128 slots 1 KB apart and concat into an i32x8 MFMA operand
__device__ __forceinline__ i32x8 ld2(const unsigned char* p) {
  i32x4 lo = *(const i32x4*)p;
  i32x4 hx = *(const i32x4*)(p + 1024);
  return __builtin_shufflevector(lo, hx, 0, 1, 2, 3, 4, 5, 6, 7);
}

// ---- kPre v2: LDS-transposed coalesced pack into fp8 fragment layouts ----
// (unchanged from R6; verified correct). One block per 32-row output tile.
// Phase 1 reads contiguous 1-KB bursts/wave, converts, XOR-swizzled LDS store;
// phase 2 gathers b128 fragment slots + 1-KB coalesced global stores.
// Xfp tile tM (16 KB): slot16 = (kb*2+h)*64 + khalf*32 + r
//   = fp8( x[tM*32+r][kb*64 + khalf*32 + h*16 + j] ), j=0..15
// Wp tile cb (32 KB): slot16 = (kb*4+ct*2+h)*64 + khalf*32 + r
//   = fp8( 16 * W[cb*64+ct*32+r][kb*64 + khalf*32 + h*16 + j] )
__global__ __launch_bounds__(256) void kPre(const float* __restrict__ x,
                                            const float* __restrict__ W,
                                            unsigned char* __restrict__ Xfp,
                                            unsigned char* __restrict__ Wp) {
  __shared__ unsigned char T[16384];
  const int tid = threadIdx.x, bid = blockIdx.x;
  const bool isX = bid < 512;
  const float* srcF;
  float scale;
  int cb = 0, half = 0;
  if (isX) {
    srcF = x + (size_t)bid * 32 * Dd;            // 32 contiguous rows
    scale = 1.0f;
  } else {
    int idx = bid - 512;                          // 0..127
    cb = idx >> 1; half = idx & 1;
    srcF = W + ((size_t)cb * 64 + half * 32) * Dd;
    scale = 16.0f;                                // x16 prescale (undone by MX scale_b)
  }

  // phase 1: fully-coalesced loads -> fp8 -> swizzled LDS
  #pragma unroll
  for (int p = 0; p < 16; ++p) {
    int f = p * 256 + tid;                        // float4 index 0..4095
    int r = f >> 7;                               // row 0..31
    int cf = f & 127;
    int c = cf >> 2, m = cf & 3;                  // 16-float chunk, float4 within
    float4 v = *(const float4*)(srcF + (size_t)f * 4);
    unsigned o = cvt4_fp8(v, scale);
    *(unsigned*)(T + ((r * 32 + (c ^ r)) * 16 + m * 4)) = o;
  }
  __syncthreads();

  // phase 2: gather fragment slots, 1-KB coalesced stores
  if (isX) {
    unsigned char* dst = Xfp + (size_t)bid * 16384;
    #pragma unroll
    for (int u = 0; u < 4; ++u) {
      int s = u * 256 + tid;                      // slot 0..1023
      int r = s & 31, khalf = (s >> 5) & 1, h = (s >> 6) & 1, kb = s >> 7;
      int c = kb * 4 + khalf * 2 + h;
      uint4 o = *(const uint4*)(T + (r * 32 + (c ^ r)) * 16);
      *(uint4*)(dst + (size_t)s * 16) = o;
    }
  } else {
    unsigned char* dst = Wp + (size_t)cb * 32768;
    #pragma unroll
    for (int u = 0; u < 4; ++u) {
      int lsl = u * 256 + tid;                    // local slot 0..1023 (ct=half)
      int r = lsl & 31, khalf = (lsl >> 5) & 1, h = (lsl >> 6) & 1, kb = lsl >> 7;
      int c = kb * 4 + khalf * 2 + h;
      int s = kb * 256 + half * 128 + h * 64 + khalf * 32 + r;
      uint4 o = *(const uint4*)(T + (r * 32 + (c ^ r)) * 16);
      *(uint4*)(dst + (size_t)s * 16) = o;
    }
  }
}

// ---- barrier-free MX-fp8 GEMM + exp-sum partials + beam scatter, M_tile=64 ----
// grid 4096, 256 threads (4 waves). Block = 64 rows x 256 cols, full K=512.
// R6 ANALYSIS: kA pinned ~92 us at both 4 and 6 blk/CU. B-panel L2 traffic =
// 32KB/wave x 4 x 8192 blocks = 1 GB ~ 30 us at the 34.5 TB/s L2 ceiling; it
// scales 1/M_tile -> 64-row blocks halve it to 0.5 GB. R1/R2's spill at this
// tile came from the FULLY-UNROLLED barrier-free K-loop letting the scheduler
// hoist all 32 B-loads; fix = #pragma unroll 1 (runtime kb bounds live ranges)
// + one af at a time + depth-1 bn prefetch only. Live ~ 64 acc + 32 B + 16 A
// + ~20 temps; estimates run ~20 high vs allocator (R4: est 95, actual 76) ->
// expect ~110 < 128 cap of (256,4). SPILL GUARD: WRITE_SIZE must stay ~11 MB.
// 4 independent MFMA chains/wave (ct x mt), 32 MFMA/wave.
__global__ __launch_bounds__(256, 4) void kA(const unsigned char* __restrict__ Xfp,
                                             const unsigned char* __restrict__ Wp,
                                             const float* __restrict__ bias,
                                             const int* __restrict__ beam,
                                             const int* __restrict__ blankp,
                                             float* __restrict__ Spart,
                                             float* __restrict__ selL,
                                             int CB) {
  __shared__ unsigned char Ald[32768];   // two packed 32-row A tiles
  __shared__ float Spw[4][64];
  __shared__ int   selv[31];
  __shared__ float selb[31];

  const int tid = threadIdx.x;
  const int tileN = blockIdx.x & 15;
  const int tileM = blockIdx.x >> 4;     // 0..255 (64-row tiles)
  const int row0 = tileM * 64, col0 = tileN * 256;
  const int bb = row0 >> 9;              // batch of this block (64 | 512)
  const int lane = tid & 63, w = tid >> 6;
  const int l31 = lane & 31, hi = lane >> 5;

  if (tid < 31) {
    int v = (tid == 0) ? *blankp : beam[bb * CB + tid - 1];
    selv[tid] = v;
    selb[tid] = bias[v];
  }

  // stage two consecutive 16-KB packed A tiles: 32 x 1KB linear DMA bursts
  const unsigned char* src = Xfp + (size_t)tileM * 32768;
  #pragma unroll
  for (int i = 0; i < 8; ++i) {
    int off = (w * 8 + i) * 1024;
    __builtin_amdgcn_global_load_lds((const GLOBAL_AS void*)(src + off + lane * 16),
                                     (LDS_AS void*)(Ald + off), 16, 0, 0);
  }
  __syncthreads();                       // only barrier before epilogue

  const int colw = col0 + w * 64;
  const int cb = tileN * 4 + w;

  f32x16 acc[2][2];                      // acc[ct][mt]
  #pragma unroll
  for (int ct = 0; ct < 2; ++ct)
    #pragma unroll
    for (int mt = 0; mt < 2; ++mt)
      #pragma unroll
      for (int r = 0; r < 16; ++r) acc[ct][mt][r] = 0.f;

  const unsigned char* wpB = Wp + (size_t)cb * 32768 + lane * 16;
  const unsigned char* aB  = Ald + lane * 16;

  i32x8 bc[2];
  bc[0] = ld2(wpB);
  bc[1] = ld2(wpB + 2048);

  #pragma unroll 1                       // REAL loop: bounds live ranges (anti-spill)
  for (int kb = 0; kb < 8; ++kb) {
    i32x8 bn[2];
    const int kn = (kb < 7) ? kb + 1 : 7;   // depth-1 B prefetch
    bn[0] = ld2(wpB + kn * 4096);
    bn[1] = ld2(wpB + kn * 4096 + 2048);
    {
      i32x8 af0 = ld2(aB + kb * 2048);               // mt = 0 tile
      acc[0][0] = __builtin_amdgcn_mfma_scale_f32_32x32x64_f8f6f4(
          af0, bc[0], acc[0][0], 0, 0, 0, 0x7f7f7f7f, 0, 0x7b7b7b7b);
      acc[1][0] = __builtin_amdgcn_mfma_scale_f32_32x32x64_f8f6f4(
          af0, bc[1], acc[1][0], 0, 0, 0, 0x7f7f7f7f, 0, 0x7b7b7b7b);
    }
    {
      i32x8 af1 = ld2(aB + 16384 + kb * 2048);       // mt = 1 tile
      acc[0][1] = __builtin_amdgcn_mfma_scale_f32_32x32x64_f8f6f4(
          af1, bc[0], acc[0][1], 0, 0, 0, 0x7f7f7f7f, 0, 0x7b7b7b7b);
      acc[1][1] = __builtin_amdgcn_mfma_scale_f32_32x32x64_f8f6f4(
          af1, bc[1], acc[1][1], 0, 0, 0, 0x7f7f7f7f, 0, 0x7b7b7b7b);
    }
    bc[0] = bn[0]; bc[1] = bn[1];
  }
  // scale_a = 2^0 (e8m0 127), scale_b = 2^-4 (123) undoes W x16 -> true logits

  // epilogue 1: row-wise sum(exp(logit+bias)) -> per-block partial (no atomics)
  // C layout (32x32): col = ct*32 + l31, row = mt*32 + (reg&3) + 8*(reg>>2) + 4*hi
  float bvl[2];
  #pragma unroll
  for (int ct = 0; ct < 2; ++ct)
    bvl[ct] = bias[colw + ct * 32 + l31] * L2E;

  #pragma unroll
  for (int mt = 0; mt < 2; ++mt) {
    #pragma unroll
    for (int reg = 0; reg < 16; ++reg) {
      float s = fexp2(acc[0][mt][reg] * L2E + bvl[0]) +
                fexp2(acc[1][mt][reg] * L2E + bvl[1]);
      s += __shfl_xor(s, 1, 64);          // reduce over 32 cols (lane bits 0..4;
      s += __shfl_xor(s, 2, 64);          //  hi-bit lanes hold different rows,
      s += __shfl_xor(s, 4, 64);          //  never mixed by this tree)
      s += __shfl_xor(s, 8, 64);
      s += __shfl_xor(s, 16, 64);
      if (l31 == 0)
        Spw[w][mt * 32 + (reg & 3) + 8 * (reg >> 2) + 4 * hi] = s;
    }
  }
  __syncthreads();
  if (tid < 64) {
    float p = Spw[0][tid] + Spw[1][tid] + Spw[2][tid] + Spw[3][tid];
    Spart[(size_t)tileN * BT + row0 + tid] = p;
  }

  // epilogue 2: beam-column scatter (raw ln-domain logit + bias).
  // selv[s]/colw wave-uniform -> readfirstlane + scalar branch skips ~29/31
  // beams with zero VALU. ct static (no runtime acc indexing).
  const int tbase = row0 & 511;
  #pragma unroll 1
  for (int s = 0; s < 31; ++s) {
    const int vsel = __builtin_amdgcn_readfirstlane(selv[s]);
    const int local = vsel - colw;
    if (local >= 0 && local < 32) {       // scalar branch, ct = 0
      const float bvs = selb[s];
      if (l31 == local) {
        #pragma unroll
        for (int mt = 0; mt < 2; ++mt)
          #pragma unroll
          for (int reg = 0; reg < 16; ++reg) {
            int t = tbase + mt * 32 + (reg & 3) + 8 * (reg >> 2) + 4 * hi;
            selL[((size_t)bb * Tt + t) * 31 + s] = acc[0][mt][reg] + bvs;
          }
      }
    } else if (local >= 32 && local < 64) {  // scalar branch, ct = 1
      const float bvs = selb[s];
      if (l31 == (local & 31)) {
        #pragma unroll
        for (int mt = 0; mt < 2; ++mt)
          #pragma unroll
          for (int reg = 0; reg < 16; ++reg) {
            int t = tbase + mt * 32 + (reg & 3) + 8 * (reg >> 2) + 4 * hi;
            selL[((size_t)bb * Tt + t) * 31 + s] = acc[1][mt][reg] + bvs;
          }
      }
    }
  }
}

// ---- CTC DP + output assembly, log2 domain. grid: B blocks x 256 threads ----
// lgS folded into sl at staging; DP depth-1 prefetch with branchless clamp.
__global__ __launch_bounds__(256) void kC(const float* __restrict__ selL,
                                          const float* __restrict__ Spart,
                                          const int* __restrict__ xl,
                                          const int* __restrict__ beam,
                                          const int* __restrict__ blankp,
                                          const int* __restrict__ eosp,
                                          float* __restrict__ out,
                                          int Ly, int CB) {
  __shared__ float sl[Tt * 31];     // log2-domain logp of selected cols
  __shared__ float lgS[Tt];         // log2(sum_exp)
  __shared__ float lastP1[Tt];      // log2-domain blank cumsum
  const int b = blockIdx.x, tid = threadIdx.x;

  for (int tt = tid; tt < Tt; tt += 256) {
    float s = 0.f;
    #pragma unroll
    for (int n = 0; n < 16; ++n) s += Spart[(size_t)n * BT + b * Tt + tt];
    lgS[tt] = flog2(s);
  }
  __syncthreads();
  for (int i = tid; i < Tt * 31; i += 256) {
    int t = i / 31;                   // const-div -> magic mul
    sl[i] = selL[(size_t)b * Tt * 31 + i] * L2E - lgS[t];
  }
  __syncthreads();

  float* orow = out + (size_t)b * Vv;
  for (int i = tid; i < Vv; i += 256) orow[i] = LOGZERO;

  const int xlb = xl[b];
  float curP = LOGZERO;
  if (tid < 64) {
    const int lane = tid;
    float vloc[8];
    float run = 0.f;
    #pragma unroll
    for (int u = 0; u < 8; ++u) {
      int t = lane * 8 + u;
      float bl = sl[t * 31];          // already log-softmax'd
      run += bl;
      vloc[u] = run;
    }
    float inc = run;
    #pragma unroll
    for (int off = 1; off < 64; off <<= 1) {
      float o = __shfl_up(inc, off, 64);
      if (lane >= off) inc += o;
    }
    float excl = inc - run;
    #pragma unroll
    for (int u = 0; u < 8; ++u) lastP1[lane * 8 + u] = vloc[u] + excl;

    const int kk = (lane < CB) ? lane : (CB - 1);
    const float LOG2ZERO = LOGZERO * L2E;
    float Pn = LOG2ZERO, Pb = LOG2ZERO;
    float mrun = -3.0e38f, srun = 0.0f;
    int start = (Ly < Tt - 1) ? Ly : (Tt - 1);
    if (start == 0) {
      Pn = sl[1 + kk];
      float vv = (0 < xlb) ? lg2add(Pn, Pb) : LOG2ZERO;
      float nm = fmaxf(mrun, vv);
      srun = srun * fexp2(mrun - nm) + fexp2(vv - nm);
      mrun = nm;
    }
    int t0 = (start > 1) ? start : 1;
    // depth-1 prefetch (branchless clamp): next iter's loads issued early so
    // LDS latency hides under the lg2add chains.
    float xn_c = sl[t0 * 31 + 1 + kk];
    float xb_c = sl[t0 * 31];
    float pf_c = lastP1[t0 - 1];      // lastPsum == lastP1 bit-exactly
    #pragma unroll 2
    for (int t = t0; t < Tt; ++t) {
      int tn = (t + 1 < Tt) ? (t + 1) : (Tt - 1);
      float xn_n = sl[tn * 31 + 1 + kk];
      float xb_n = sl[tn * 31];
      float pf_n = lastP1[tn - 1];
      float Pn2 = lg2add(Pn, pf_c) + xn_c;
      float Pb2 = lg2add(Pn, Pb) + xb_c;
      Pn = Pn2; Pb = Pb2;
      float vv = (t < xlb) ? lg2add(Pn, Pb) : LOG2ZERO;   // off critical path
      float nm = fmaxf(mrun, vv);
      srun = srun * fexp2(mrun - nm) + fexp2(vv - nm);
      mrun = nm;
      xn_c = xn_n; xb_c = xb_n; pf_c = pf_n;
    }
    curP = (mrun + flog2(srun)) * LN2;       // back to ln domain
  }
  __syncthreads();   // LOGZERO fill + lastP1 complete

  if (tid < 64) {
    if (tid < CB) orow[beam[b * CB + tid]] = curP;
  }
  __syncthreads();
  if (tid == 0) {
    float eosv = (xlb >= 1) ? lastP1[xlb - 1] * LN2 : 0.0f;
    orow[*eosp] = eosv;
    orow[*blankp] = LOGZERO;
  }
}

extern "C" void kernel_launch(void* const* d_in, const int* in_sizes, int n_in,
                              void* d_out, int out_size, void* d_ws, size_t ws_size,
                              hipStream_t stream) {
  (void)n_in; (void)out_size; (void)ws_size;
  const float* x    = (const float*)d_in[0];
  const float* W    = (const float*)d_in[1];
  const float* bias = (const float*)d_in[2];
  const int* xl     = (const int*)d_in[3];
  const int* beam   = (const int*)d_in[5];
  const int* blankp = (const int*)d_in[6];
  const int* eosp   = (const int*)d_in[7];
  const int Ly = in_sizes[4] / Bb;
  const int CB = in_sizes[5] / Bb;

  float* Spart = (float*)d_ws;                                            // 1 MB
  float* selL  = (float*)((char*)d_ws + (size_t)0x100000);                // 2.03 MB
  unsigned char* Xfp = (unsigned char*)((char*)d_ws + (size_t)0x400000);  // 8 MB
  unsigned char* Wp  = (unsigned char*)((char*)d_ws + (size_t)0xC00000);  // 2 MB
  float* outf = (float*)d_out;

  kPre<<<640, 256, 0, stream>>>(x, W, Xfp, Wp);
  kA<<<4096, 256, 0, stream>>>(Xfp, Wp, bias, beam, blankp, Spart, selL, CB);
  kC<<<Bb, 256, 0, stream>>>(selL, Spart, xl, beam, blankp, eosp, outf, Ly, CB);
}

// Round 8
// 206.114 us; speedup vs baseline: 1.1303x; 1.1300x over previous
//
#include <hip/hip_runtime.h>
#include <hip/hip_fp8.h>

#define LOGZERO -4290774016.0f   // -(65504^2), exactly representable in fp32
#define L2E 1.4426950408889634f  // log2(e)
#define LN2 0.6931471805599453f

constexpr int Bb = 32, Tt = 512, Dd = 512, Vv = 4096;
constexpr int BT = Bb * Tt;

typedef __attribute__((ext_vector_type(4)))  float f32x4;
typedef __attribute__((ext_vector_type(16))) float f32x16;
typedef __attribute__((ext_vector_type(4)))  int   i32x4;
typedef __attribute__((ext_vector_type(8)))  int   i32x8;

#define GLOBAL_AS __attribute__((address_space(1)))
#define LDS_AS    __attribute__((address_space(3)))

__device__ __forceinline__ float fexp2(float x) { return __builtin_amdgcn_exp2f(x); }  // 2^x
__device__ __forceinline__ float flog2(float x) { return __builtin_amdgcn_logf(x); }   // log2(x)

// pack 4 floats (scaled) -> 4 OCP e4m3 bytes
__device__ __forceinline__ unsigned cvt4_fp8(float4 v, float s) {
#if __has_builtin(__builtin_amdgcn_cvt_pk_fp8_f32)
  int p = __builtin_amdgcn_cvt_pk_fp8_f32(v.x * s, v.y * s, 0, false);
  p = __builtin_amdgcn_cvt_pk_fp8_f32(v.z * s, v.w * s, p, true);
  return (unsigned)p;
#else
  unsigned b0 = __hip_cvt_float_to_fp8(v.x * s, __HIP_SATFINITE, __HIP_E4M3);
  unsigned b1 = __hip_cvt_float_to_fp8(v.y * s, __HIP_SATFINITE, __HIP_E4M3);
  unsigned b2 = __hip_cvt_float_to_fp8(v.z * s, __HIP_SATFINITE, __HIP_E4M3);
  unsigned b3 = __hip_cvt_float_to_fp8(v.w * s, __HIP_SATFINITE, __HIP_E4M3);
  return b0 | (b1 << 8) | (b2 << 16) | (b3 << 24);
#endif
}

// logaddexp in the log2 domain
__device__ __forceinline__ float lg2add(float a, float b) {
  float mx = fmaxf(a, b);
  float d  = fabsf(a - b);
  return mx + flog2(1.0f + fexp2(-d));
}

// load two b128 slots 1 KB apart and concat into an i32x8 MFMA operand
__device__ __forceinline__ i32x8 ld2(const unsigned char* p) {
  i32x4 lo = *(const i32x4*)p;
  i32x4 hx = *(const i32x4*)(p + 1024);
  return __builtin_shufflevector(lo, hx, 0, 1, 2, 3, 4, 5, 6, 7);
}

// ---- kPre: pack x and W into fp8 FRAGMENT-ORDER layouts (R5 version -----
// reverted: R6's LDS-transposed kPre + kC rewrite cost +11 us total with kA
// constant; this variant is part of the measured-best 221.9 us state).
// Xfp (32-row tiles, 16 KB each): slot16 = tM*1024 + (kb*2+h)*64 + khalf*32 + r
//   = fp8( x[tM*32 + r][kb*64 + khalf*32 + h*16 + j] ), j=0..15
// Wp: slot16 = cb*2048 + (kb*4 + ct*2 + h)*64 + khalf*32 + r
//   = fp8( 16 * W[cb*64 + ct*32 + r][kb*64 + khalf*32 + h*16 + j] )
__global__ __launch_bounds__(256) void kPre(const float* __restrict__ x,
                                            const float* __restrict__ W,
                                            unsigned char* __restrict__ Xfp,
                                            unsigned char* __restrict__ Wp) {
  const int t = blockIdx.x * 256 + threadIdx.x;
  if (t < 524288) {                     // X part: 8 MB / 16 B = 524288 slots
    const int tM = t >> 10, s = t & 1023;       // tM = 0..511 (32-row tiles)
    const int l = s & 63, h = (s >> 6) & 1, kb = s >> 7;   // kb = 0..7
    const int row = tM * 32 + (l & 31);
    const int col = kb * 64 + ((l >> 5) << 5) + h * 16;
    const float* p = x + (size_t)row * Dd + col;
    uint4 o;
    o.x = cvt4_fp8(*(const float4*)p, 1.0f);
    o.y = cvt4_fp8(*(const float4*)(p + 4), 1.0f);
    o.z = cvt4_fp8(*(const float4*)(p + 8), 1.0f);
    o.w = cvt4_fp8(*(const float4*)(p + 12), 1.0f);
    *(uint4*)(Xfp + (size_t)t * 16) = o;
  } else {                              // W part: 2 MB / 16 B = 131072 slots
    const int tt = t - 524288;
    const int cb = tt >> 11, s = tt & 2047;
    const int l = s & 63, h = (s >> 6) & 1, ct = (s >> 7) & 1, kb = s >> 8;
    const int row = cb * 64 + ct * 32 + (l & 31);
    const int col = kb * 64 + ((l >> 5) << 5) + h * 16;
    const float* p = W + (size_t)row * Dd + col;
    uint4 o;
    o.x = cvt4_fp8(*(const float4*)p, 16.0f);       // x16 prescale into e4m3 range
    o.y = cvt4_fp8(*(const float4*)(p + 4), 16.0f); // (undone by MX scale_b = 2^-4)
    o.z = cvt4_fp8(*(const float4*)(p + 8), 16.0f);
    o.w = cvt4_fp8(*(const float4*)(p + 12), 16.0f);
    *(uint4*)(Wp + (size_t)tt * 16) = o;
  }
}

// ---- barrier-free MX-fp8 GEMM + exp-sum partials + beam scatter, M_tile=64 ----
// grid 4096, 256 threads (4 waves). Block = 64 rows x 256 cols, full K=512.
// K-loop unchanged from R7 (unroll 1, depth-1 B prefetch, 60 VGPR, no spill).
// R7 ANALYSIS: kA pinned ~91.5 us across 2/4/6 blk/CU, 32/64-row tiles, and
// halved L2 traffic. The invariant cost: the epilogue's 5-stage shuffle
// butterfly = 160 ds_swizzle/thread ~ 25 us/CU of DS-pipe time (the largest
// non-MFMA term; bank conflicts 0 but raw DS throughput ~5.8 cyc/op).
// EPILOGUE v2: write ct-summed partials to a [64 row][128 col] f32 LDS
// matrix (reusing Ald, dead after the K-loop) with chunk-XOR swizzle
// (chunk' = chunk ^ (row&31); conflict-free writes AND reads; sum is
// permutation-invariant so the read side just XORs its loop index);
// 64 threads row-sum via 32 x ds_read_b128. DS instr/thread: 160 -> ~40,
// and the 160 butterfly adds leave the VALU stream.
__global__ __launch_bounds__(256, 4) void kA(const unsigned char* __restrict__ Xfp,
                                             const unsigned char* __restrict__ Wp,
                                             const float* __restrict__ bias,
                                             const int* __restrict__ beam,
                                             const int* __restrict__ blankp,
                                             float* __restrict__ Spart,
                                             float* __restrict__ selL,
                                             int CB) {
  __shared__ unsigned char Ald[32768];   // A tiles; reused as 64x128 f32 P-matrix
  __shared__ int   selv[31];
  __shared__ float selb[31];

  const int tid = threadIdx.x;
  const int tileN = blockIdx.x & 15;
  const int tileM = blockIdx.x >> 4;     // 0..255 (64-row tiles)
  const int row0 = tileM * 64, col0 = tileN * 256;
  const int bb = row0 >> 9;              // batch of this block (64 | 512)
  const int lane = tid & 63, w = tid >> 6;
  const int l31 = lane & 31, hi = lane >> 5;

  if (tid < 31) {
    int v = (tid == 0) ? *blankp : beam[bb * CB + tid - 1];
    selv[tid] = v;
    selb[tid] = bias[v];
  }

  // stage two consecutive 16-KB packed A tiles: 32 x 1KB linear DMA bursts
  const unsigned char* src = Xfp + (size_t)tileM * 32768;
  #pragma unroll
  for (int i = 0; i < 8; ++i) {
    int off = (w * 8 + i) * 1024;
    __builtin_amdgcn_global_load_lds((const GLOBAL_AS void*)(src + off + lane * 16),
                                     (LDS_AS void*)(Ald + off), 16, 0, 0);
  }
  __syncthreads();

  const int colw = col0 + w * 64;
  const int cb = tileN * 4 + w;

  f32x16 acc[2][2];                      // acc[ct][mt]
  #pragma unroll
  for (int ct = 0; ct < 2; ++ct)
    #pragma unroll
    for (int mt = 0; mt < 2; ++mt)
      #pragma unroll
      for (int r = 0; r < 16; ++r) acc[ct][mt][r] = 0.f;

  const unsigned char* wpB = Wp + (size_t)cb * 32768 + lane * 16;
  const unsigned char* aB  = Ald + lane * 16;

  i32x8 bc[2];
  bc[0] = ld2(wpB);
  bc[1] = ld2(wpB + 2048);

  #pragma unroll 1                       // REAL loop: bounds live ranges (anti-spill)
  for (int kb = 0; kb < 8; ++kb) {
    i32x8 bn[2];
    const int kn = (kb < 7) ? kb + 1 : 7;   // depth-1 B prefetch
    bn[0] = ld2(wpB + kn * 4096);
    bn[1] = ld2(wpB + kn * 4096 + 2048);
    {
      i32x8 af0 = ld2(aB + kb * 2048);               // mt = 0 tile
      acc[0][0] = __builtin_amdgcn_mfma_scale_f32_32x32x64_f8f6f4(
          af0, bc[0], acc[0][0], 0, 0, 0, 0x7f7f7f7f, 0, 0x7b7b7b7b);
      acc[1][0] = __builtin_amdgcn_mfma_scale_f32_32x32x64_f8f6f4(
          af0, bc[1], acc[1][0], 0, 0, 0, 0x7f7f7f7f, 0, 0x7b7b7b7b);
    }
    {
      i32x8 af1 = ld2(aB + 16384 + kb * 2048);       // mt = 1 tile
      acc[0][1] = __builtin_amdgcn_mfma_scale_f32_32x32x64_f8f6f4(
          af1, bc[0], acc[0][1], 0, 0, 0, 0x7f7f7f7f, 0, 0x7b7b7b7b);
      acc[1][1] = __builtin_amdgcn_mfma_scale_f32_32x32x64_f8f6f4(
          af1, bc[1], acc[1][1], 0, 0, 0, 0x7f7f7f7f, 0, 0x7b7b7b7b);
    }
    bc[0] = bn[0]; bc[1] = bn[1];
  }
  // scale_a = 2^0 (e8m0 127), scale_b = 2^-4 (123) undoes W x16 -> true logits

  // epilogue 1 v2: LDS-matrix row-sum.
  // C layout (32x32): col = ct*32 + l31, row = mt*32 + (reg&3)+8*(reg>>2)+4*hi.
  // P[row][f], f = w*32+l31; lane writes 32 partials (one per row it holds),
  // 16-B chunk index swizzled by row&31. Then 64 threads sum their row.
  __syncthreads();                       // all waves done reading Ald
  float* P = (float*)Ald;

  float bvl[2];
  #pragma unroll
  for (int ct = 0; ct < 2; ++ct)
    bvl[ct] = bias[colw + ct * 32 + l31] * L2E;

  {
    const int f = w * 32 + l31;          // 0..127
    const int chunk = f >> 2, elem = f & 3;
    #pragma unroll
    for (int mt = 0; mt < 2; ++mt) {
      #pragma unroll
      for (int reg = 0; reg < 16; ++reg) {
        float s = fexp2(acc[0][mt][reg] * L2E + bvl[0]) +
                  fexp2(acc[1][mt][reg] * L2E + bvl[1]);
        int r31 = (reg & 3) + 8 * (reg >> 2) + 4 * hi;   // row & 31
        int row = mt * 32 + r31;
        P[row * 128 + ((chunk ^ r31) << 2) + elem] = s;
      }
    }
  }
  __syncthreads();
  if (tid < 64) {
    const int r31 = tid & 31;
    f32x4 v = {0.f, 0.f, 0.f, 0.f};
    #pragma unroll
    for (int i = 0; i < 32; ++i)         // read all 32 chunks, XOR order
      v += *(const f32x4*)&P[tid * 128 + ((i ^ r31) << 2)];
    Spart[(size_t)tileN * BT + row0 + tid] = v[0] + v[1] + v[2] + v[3];
  }

  // epilogue 2: beam-column scatter (raw ln-domain logit + bias).
  // selv[s]/colw wave-uniform -> readfirstlane + scalar branch skips ~29/31
  // beams with zero VALU. ct static (no runtime acc indexing).
  const int tbase = row0 & 511;
  #pragma unroll 1
  for (int s = 0; s < 31; ++s) {
    const int vsel = __builtin_amdgcn_readfirstlane(selv[s]);
    const int local = vsel - colw;
    if (local >= 0 && local < 32) {       // scalar branch, ct = 0
      const float bvs = selb[s];
      if (l31 == local) {
        #pragma unroll
        for (int mt = 0; mt < 2; ++mt)
          #pragma unroll
          for (int reg = 0; reg < 16; ++reg) {
            int t = tbase + mt * 32 + (reg & 3) + 8 * (reg >> 2) + 4 * hi;
            selL[((size_t)bb * Tt + t) * 31 + s] = acc[0][mt][reg] + bvs;
          }
      }
    } else if (local >= 32 && local < 64) {  // scalar branch, ct = 1
      const float bvs = selb[s];
      if (l31 == (local & 31)) {
        #pragma unroll
        for (int mt = 0; mt < 2; ++mt)
          #pragma unroll
          for (int reg = 0; reg < 16; ++reg) {
            int t = tbase + mt * 32 + (reg & 3) + 8 * (reg >> 2) + 4 * hi;
            selL[((size_t)bb * Tt + t) * 31 + s] = acc[1][mt][reg] + bvs;
          }
      }
    }
  }
}

// ---- CTC DP + output assembly, log2 domain (R5 version, reverted) ----
__global__ __launch_bounds__(256) void kC(const float* __restrict__ selL,
                                          const float* __restrict__ Spart,
                                          const int* __restrict__ xl,
                                          const int* __restrict__ beam,
                                          const int* __restrict__ blankp,
                                          const int* __restrict__ eosp,
                                          float* __restrict__ out,
                                          int Ly, int CB) {
  __shared__ float sl[Tt * 31];     // raw logits * log2(e)
  __shared__ float lgS[Tt];         // log2(sum_exp)
  __shared__ float lastP1[Tt];      // log2-domain blank cumsum
  __shared__ float blankLp[Tt];     // log2-domain blank logp
  const int b = blockIdx.x, tid = threadIdx.x;

  for (int i = tid; i < Tt * 31; i += 256)
    sl[i] = selL[(size_t)b * Tt * 31 + i] * L2E;
  for (int tt = tid; tt < Tt; tt += 256) {
    float s = 0.f;
    #pragma unroll
    for (int n = 0; n < 16; ++n) s += Spart[(size_t)n * BT + b * Tt + tt];
    lgS[tt] = flog2(s);
  }
  __syncthreads();

  float* orow = out + (size_t)b * Vv;
  for (int i = tid; i < Vv; i += 256) orow[i] = LOGZERO;

  const int xlb = xl[b];
  float curP = LOGZERO;
  if (tid < 64) {
    const int lane = tid;
    float vloc[8];
    float run = 0.f;
    #pragma unroll
    for (int u = 0; u < 8; ++u) {
      int t = lane * 8 + u;
      float bl = sl[t * 31] - lgS[t];
      blankLp[t] = bl;
      run += bl;
      vloc[u] = run;
    }
    float inc = run;
    #pragma unroll
    for (int off = 1; off < 64; off <<= 1) {
      float o = __shfl_up(inc, off, 64);
      if (lane >= off) inc += o;
    }
    float excl = inc - run;
    #pragma unroll
    for (int u = 0; u < 8; ++u) lastP1[lane * 8 + u] = vloc[u] + excl;

    const int kk = (lane < CB) ? lane : (CB - 1);
    const float LOG2ZERO = LOGZERO * L2E;
    float Pn = LOG2ZERO, Pb = LOG2ZERO;
    float mrun = -3.0e38f, srun = 0.0f;
    int start = (Ly < Tt - 1) ? Ly : (Tt - 1);
    if (start == 0) {
      Pn = sl[1 + kk] - lgS[0];
      float vv = (0 < xlb) ? lg2add(Pn, Pb) : LOG2ZERO;
      float nm = fmaxf(mrun, vv);
      srun = srun * fexp2(mrun - nm) + fexp2(vv - nm);
      mrun = nm;
    }
    int t0 = (start > 1) ? start : 1;
    #pragma unroll 2
    for (int t = t0; t < Tt; ++t) {
      float xn = sl[t * 31 + 1 + kk] - lgS[t];
      float xb = blankLp[t];
      float pref = lastP1[t - 1];   // lastPsum == lastP1 bit-exactly
      float Pn2 = lg2add(Pn, pref) + xn;
      float Pb2 = lg2add(Pn, Pb) + xb;
      Pn = Pn2; Pb = Pb2;
      float vv = (t < xlb) ? lg2add(Pn, Pb) : LOG2ZERO;   // off critical path
      float nm = fmaxf(mrun, vv);
      srun = srun * fexp2(mrun - nm) + fexp2(vv - nm);
      mrun = nm;
    }
    curP = (mrun + flog2(srun)) * LN2;       // back to ln domain
  }
  __syncthreads();   // LOGZERO fill + lastP1 complete

  if (tid < 64) {
    if (tid < CB) orow[beam[b * CB + tid]] = curP;
  }
  __syncthreads();
  if (tid == 0) {
    float eosv = (xlb >= 1) ? lastP1[xlb - 1] * LN2 : 0.0f;
    orow[*eosp] = eosv;
    orow[*blankp] = LOGZERO;
  }
}

extern "C" void kernel_launch(void* const* d_in, const int* in_sizes, int n_in,
                              void* d_out, int out_size, void* d_ws, size_t ws_size,
                              hipStream_t stream) {
  (void)n_in; (void)out_size; (void)ws_size;
  const float* x    = (const float*)d_in[0];
  const float* W    = (const float*)d_in[1];
  const float* bias = (const float*)d_in[2];
  const int* xl     = (const int*)d_in[3];
  const int* beam   = (const int*)d_in[5];
  const int* blankp = (const int*)d_in[6];
  const int* eosp   = (const int*)d_in[7];
  const int Ly = in_sizes[4] / Bb;
  const int CB = in_sizes[5] / Bb;

  float* Spart = (float*)d_ws;                                            // 1 MB
  float* selL  = (float*)((char*)d_ws + (size_t)0x100000);                // 2.03 MB
  unsigned char* Xfp = (unsigned char*)((char*)d_ws + (size_t)0x400000);  // 8 MB
  unsigned char* Wp  = (unsigned char*)((char*)d_ws + (size_t)0xC00000);  // 2 MB
  float* outf = (float*)d_out;

  kPre<<<2560, 256, 0, stream>>>(x, W, Xfp, Wp);
  kA<<<4096, 256, 0, stream>>>(Xfp, Wp, bias, beam, blankp, Spart, selL, CB);
  kC<<<Bb, 256, 0, stream>>>(selL, Spart, xl, beam, blankp, eosp, outf, Ly, CB);
}